// Round 1
// baseline (1413.376 us; speedup 1.0000x reference)
//
#include <hip/hip_runtime.h>

// Problem constants (GraphNet_41944650613153)
#define NN    156            // nodes per graph
#define CN    128            // hidden/out channels
#define CIN   301            // input channels
#define BATCH 1024
#define M_ROWS (BATCH * NN)  // 159744 = 1248 * 128 exactly
#define BM    128            // GEMM rows per block
#define KT    16             // GEMM K tile
#define LDA   132            // padded LDS stride (128+4 keeps float4 align, breaks conflicts)
#define LDB   132

// ---------------------------------------------------------------------------
// prep: degree -> dinv -> CSR (by destination col), self-loops included.
// Single block; trivial cost. nnz = E + NN (<= 2048 assumed; actual 1720).
// ---------------------------------------------------------------------------
__global__ __launch_bounds__(256) void prep_kernel(const int* __restrict__ ei, int E,
        int* __restrict__ rowptr, int* __restrict__ srcs, float* __restrict__ vals) {
    __shared__ int   cnt[NN];
    __shared__ int   pos[NN];
    __shared__ float dinv_s[NN];
    const int t = threadIdx.x;
    for (int n = t; n < NN; n += 256) cnt[n] = 1;          // self loop
    __syncthreads();
    for (int e = t; e < E; e += 256) atomicAdd(&cnt[ei[E + e]], 1);
    __syncthreads();
    for (int n = t; n < NN; n += 256) dinv_s[n] = rsqrtf((float)cnt[n]);
    __syncthreads();
    if (t == 0) {
        int run = 0;
        for (int n = 0; n < NN; n++) { rowptr[n] = run; pos[n] = run; run += cnt[n]; }
        rowptr[NN] = run;
    }
    __syncthreads();
    for (int e = t; e < E; e += 256) {
        const int r = ei[e], c = ei[E + e];
        const int idx = atomicAdd(&pos[c], 1);
        srcs[idx] = r;
        vals[idx] = dinv_s[r] * dinv_s[c];
    }
    for (int n = t; n < NN; n += 256) {
        const int idx = atomicAdd(&pos[n], 1);
        srcs[idx] = n;
        vals[idx] = dinv_s[n] * dinv_s[n];
    }
}

// ---------------------------------------------------------------------------
// fp32 GEMM: C[M,128] = A[M,K] @ W[K,128] (+bias). 128x128 block tile,
// 8x8 per-thread register tile, K staged in 16-deep LDS tiles.
// A is staged transposed (As[k][r]) so per-thread row reads are float4.
// NOTE: safe to call with C == A (in-place): each row is read only by the
// block that writes it, and all reads complete before the epilogue stores.
// ---------------------------------------------------------------------------
template<int ADD_BIAS>
__global__ __launch_bounds__(256) void gemm_kernel(const float* A, const float* __restrict__ W,
        const float* __restrict__ bias, float* C, int K) {
    __shared__ float As[KT][LDA];
    __shared__ float Bs[KT][LDB];
    const int t = threadIdx.x;
    const size_t row0 = (size_t)blockIdx.x * BM;
    const int c0 = (t & 15) * 8;
    const int r0 = (t >> 4) * 8;
    float acc[8][8];
#pragma unroll
    for (int i = 0; i < 8; i++)
#pragma unroll
        for (int j = 0; j < 8; j++) acc[i][j] = 0.f;

    const int nk = (K + KT - 1) / KT;
    for (int kt = 0; kt < nk; kt++) {
        const int k0 = kt * KT;
        // stage A tile (128 rows x 16 k), transposed into LDS
#pragma unroll
        for (int ii = 0; ii < (BM * KT) / 256; ii++) {
            const int i = t + ii * 256;
            const int k = i & (KT - 1), r = i >> 4;
            const int kk = k0 + k;
            As[k][r] = (kk < K) ? A[(row0 + r) * K + kk] : 0.f;
        }
        // stage W tile (16 k x 128 c), coalesced
#pragma unroll
        for (int ii = 0; ii < (KT * CN) / 256; ii++) {
            const int i = t + ii * 256;
            const int k = i >> 7, c = i & (CN - 1);
            const int kk = k0 + k;
            Bs[k][c] = (kk < K) ? W[(size_t)kk * CN + c] : 0.f;
        }
        __syncthreads();
#pragma unroll
        for (int k = 0; k < KT; k++) {
            const float4 a0  = *(const float4*)&As[k][r0];
            const float4 a1  = *(const float4*)&As[k][r0 + 4];
            const float4 bv0 = *(const float4*)&Bs[k][c0];
            const float4 bv1 = *(const float4*)&Bs[k][c0 + 4];
            const float av[8] = {a0.x, a0.y, a0.z, a0.w, a1.x, a1.y, a1.z, a1.w};
            const float bv[8] = {bv0.x, bv0.y, bv0.z, bv0.w, bv1.x, bv1.y, bv1.z, bv1.w};
#pragma unroll
            for (int i = 0; i < 8; i++)
#pragma unroll
                for (int j = 0; j < 8; j++)
                    acc[i][j] = fmaf(av[i], bv[j], acc[i][j]);
        }
        __syncthreads();
    }

    float4 bia0 = make_float4(0.f, 0.f, 0.f, 0.f), bia1 = bia0;
    if (ADD_BIAS) {
        bia0 = *(const float4*)(bias + c0);
        bia1 = *(const float4*)(bias + c0 + 4);
    }
#pragma unroll
    for (int i = 0; i < 8; i++) {
        const size_t off = (row0 + r0 + i) * CN + c0;
        float4 o0 = make_float4(acc[i][0] + bia0.x, acc[i][1] + bia0.y,
                                acc[i][2] + bia0.z, acc[i][3] + bia0.w);
        float4 o1 = make_float4(acc[i][4] + bia1.x, acc[i][5] + bia1.y,
                                acc[i][6] + bia1.z, acc[i][7] + bia1.w);
        *(float4*)(C + off)     = o0;
        *(float4*)(C + off + 4) = o1;
    }
}

// ---------------------------------------------------------------------------
// Aggregation: out[b,n,:] = sum_{e in CSR[n]} t[b,src_e,:] * val_e, optionally
// fused with (conv-bias + eval-BN + ReLU):  relu(agg*s + (b*s + bnb)),
// s = bn_w / sqrt(1+eps).  One block per batch entry; t[b] (80 KB) is
// L1/L2-resident, gathers are 512B-row coalesced float4 reads.
// ---------------------------------------------------------------------------
template<int BN_RELU>
__global__ __launch_bounds__(256) void agg_kernel(const float* __restrict__ tin,
        const int* __restrict__ rowptr, const int* __restrict__ srcs,
        const float* __restrict__ vals,
        const float* __restrict__ conv_b, const float* __restrict__ bn_w,
        const float* __restrict__ bn_b, float* __restrict__ out) {
    const int b = blockIdx.x;
    const int t = threadIdx.x;
    const int c0 = (t & 31) * 4;   // 4 consecutive channels per thread
    const int ng = t >> 5;         // 8 nodes processed per block iteration

    float4 sc = make_float4(1.f, 1.f, 1.f, 1.f);
    float4 sh = make_float4(0.f, 0.f, 0.f, 0.f);
    if (BN_RELU) {
        const float inv = rsqrtf(1.f + 1e-5f);
        const float4 w  = *(const float4*)(bn_w + c0);
        const float4 bb = *(const float4*)(bn_b + c0);
        const float4 cb = *(const float4*)(conv_b + c0);
        sc = make_float4(w.x * inv, w.y * inv, w.z * inv, w.w * inv);
        sh = make_float4(fmaf(cb.x, sc.x, bb.x), fmaf(cb.y, sc.y, bb.y),
                         fmaf(cb.z, sc.z, bb.z), fmaf(cb.w, sc.w, bb.w));
    }

    const float* tb = tin + (size_t)b * (NN * CN);
    float*       ob = out + (size_t)b * (NN * CN);

    for (int n0 = 0; n0 < NN; n0 += 8) {
        const int n = n0 + ng;
        if (n < NN) {
            const int beg = rowptr[n], end = rowptr[n + 1];
            float4 acc = make_float4(0.f, 0.f, 0.f, 0.f);
            for (int i = beg; i < end; i++) {
                const int s = srcs[i];
                const float v = vals[i];
                const float4 tv = *(const float4*)(tb + s * CN + c0);
                acc.x = fmaf(tv.x, v, acc.x);
                acc.y = fmaf(tv.y, v, acc.y);
                acc.z = fmaf(tv.z, v, acc.z);
                acc.w = fmaf(tv.w, v, acc.w);
            }
            if (BN_RELU) {
                acc.x = fmaxf(fmaf(acc.x, sc.x, sh.x), 0.f);
                acc.y = fmaxf(fmaf(acc.y, sc.y, sh.y), 0.f);
                acc.z = fmaxf(fmaf(acc.z, sc.z, sh.z), 0.f);
                acc.w = fmaxf(fmaf(acc.w, sc.w, sh.w), 0.f);
            }
            *(float4*)(ob + n * CN + c0) = acc;
        }
    }
}

// ---------------------------------------------------------------------------
// Orchestration. Buffers:
//   d_out  : GEMM scratch for layers 0/1, aggregated input for layer 2,
//            final output (in-place GEMM).
//   d_ws   : [CSR header 64KB][bufA: 159744*128 floats = 81.8 MB]
// Layer 2 uses S·(h@W2)+b2 == (S·h)@W2+b2 to avoid a second scratch buffer.
// ---------------------------------------------------------------------------
extern "C" void kernel_launch(void* const* d_in, const int* in_sizes, int n_in,
                              void* d_out, int out_size, void* d_ws, size_t ws_size,
                              hipStream_t stream) {
    const float* x    = (const float*)d_in[0];
    const int*   ei   = (const int*)  d_in[1];
    const float* W0   = (const float*)d_in[2];
    const float* b0   = (const float*)d_in[3];
    const float* bnw0 = (const float*)d_in[4];
    const float* bnb0 = (const float*)d_in[5];
    const float* W1   = (const float*)d_in[6];
    const float* b1   = (const float*)d_in[7];
    const float* bnw1 = (const float*)d_in[8];
    const float* bnb1 = (const float*)d_in[9];
    const float* W2   = (const float*)d_in[10];
    const float* b2   = (const float*)d_in[11];
    float* out = (float*)d_out;

    const int E = in_sizes[1] / 2;

    int*   rowptr = (int*)d_ws;            // 157 ints
    int*   srcs   = rowptr + 512;          // up to 2048
    float* vals   = (float*)(srcs + 2048); // up to 2048
    float* bufA   = (float*)d_ws + 16384;  // 64 KB offset, 81.8 MB

    const int gemm_grid = M_ROWS / BM;     // 1248, exact

    prep_kernel<<<1, 256, 0, stream>>>(ei, E, rowptr, srcs, vals);

    // Layer 0: t0 = x@W0 -> d_out ; h1 = relu(bn(agg(t0)+b0)) -> bufA
    gemm_kernel<0><<<gemm_grid, 256, 0, stream>>>(x, W0, nullptr, out, CIN);
    agg_kernel<1><<<BATCH, 256, 0, stream>>>(out, rowptr, srcs, vals, b0, bnw0, bnb0, bufA);

    // Layer 1: t1 = h1@W1 -> d_out ; h2 = relu(bn(agg(t1)+b1)) -> bufA
    gemm_kernel<0><<<gemm_grid, 256, 0, stream>>>(bufA, W1, nullptr, out, CN);
    agg_kernel<1><<<BATCH, 256, 0, stream>>>(out, rowptr, srcs, vals, b1, bnw1, bnb1, bufA);

    // Layer 2 (reordered): g = agg(h2) -> d_out ; out = g@W2 + b2 (in-place)
    agg_kernel<0><<<BATCH, 256, 0, stream>>>(bufA, rowptr, srcs, vals, nullptr, nullptr, nullptr, out);
    gemm_kernel<1><<<gemm_grid, 256, 0, stream>>>(out, W2, b2, out, CN);
}

// Round 2
// 1038.193 us; speedup vs baseline: 1.3614x; 1.3614x over previous
//
#include <hip/hip_runtime.h>

// Problem constants (GraphNet_41944650613153)
#define NN    156            // nodes per graph
#define CN    128            // hidden/out channels
#define BATCH 1024
#define M_ROWS (BATCH * NN)  // 159744 = 1248 * 128 exactly

typedef __attribute__((ext_vector_type(8))) short bf16x8;  // 8 bf16 (4 VGPRs)
typedef __attribute__((ext_vector_type(4))) float f32x4;   // 4 fp32 acc

// Pre-transposed, hi/lo-split weights: Wt[n][k] = W[k][n], zero-padded to Kpad.
// Device globals (module memory): avoids gambling on ws_size slack.
#define KP0 320
#define W0_OFF 0
#define W1_OFF (128 * KP0)
#define W2_OFF (128 * KP0 + 128 * 128)
__device__ ushort g_WtH[128 * (KP0 + 128 + 128)];
__device__ ushort g_WtL[128 * (KP0 + 128 + 128)];

__device__ __forceinline__ ushort bf16_rne(float f) {
    union { float f; uint32_t u; } v; v.f = f;
    return (ushort)((v.u + 0x7FFFu + ((v.u >> 16) & 1u)) >> 16);
}
__device__ __forceinline__ float bf16_f(ushort h) {
    union { float f; uint32_t u; } v; v.u = ((uint32_t)h) << 16; return v.f;
}
__device__ __forceinline__ ushort bf16_trunc(float f) {   // chop: fine for the lo term
    union { float f; uint32_t u; } v; v.f = f;
    return (ushort)(v.u >> 16);
}

// ---------------------------------------------------------------------------
// prep: degree -> dinv -> CSR (by destination col), self-loops included.
// ---------------------------------------------------------------------------
__global__ __launch_bounds__(256) void prep_kernel(const int* __restrict__ ei, int E,
        int* __restrict__ rowptr, int* __restrict__ srcs, float* __restrict__ vals) {
    __shared__ int   cnt[NN];
    __shared__ int   pos[NN];
    __shared__ float dinv_s[NN];
    const int t = threadIdx.x;
    for (int n = t; n < NN; n += 256) cnt[n] = 1;          // self loop
    __syncthreads();
    for (int e = t; e < E; e += 256) atomicAdd(&cnt[ei[E + e]], 1);
    __syncthreads();
    for (int n = t; n < NN; n += 256) dinv_s[n] = rsqrtf((float)cnt[n]);
    __syncthreads();
    if (t == 0) {
        int run = 0;
        for (int n = 0; n < NN; n++) { rowptr[n] = run; pos[n] = run; run += cnt[n]; }
        rowptr[NN] = run;
    }
    __syncthreads();
    for (int e = t; e < E; e += 256) {
        const int r = ei[e], c = ei[E + e];
        const int idx = atomicAdd(&pos[c], 1);
        srcs[idx] = r;
        vals[idx] = dinv_s[r] * dinv_s[c];
    }
    for (int n = t; n < NN; n += 256) {
        const int idx = atomicAdd(&pos[n], 1);
        srcs[idx] = n;
        vals[idx] = dinv_s[n] * dinv_s[n];
    }
}

// ---------------------------------------------------------------------------
// W transpose + hi/lo split: g_Wt{H,L}[woff + n*Kpad + k] = split(W[k][n]).
// Tiny volume; coalesced on the W read side.
// ---------------------------------------------------------------------------
__global__ __launch_bounds__(256) void wt_kernel(const float* __restrict__ W,
        int K, int Kpad, int woff) {
    const int id = blockIdx.x * 256 + threadIdx.x;   // over 128*Kpad, exact grid
    const int n = id & 127, k = id >> 7;
    const float f = (k < K) ? W[(size_t)k * CN + n] : 0.f;
    const ushort h = bf16_rne(f);
    g_WtH[woff + n * Kpad + k] = h;
    g_WtL[woff + n * Kpad + k] = bf16_trunc(f - bf16_f(h));
}

// ---------------------------------------------------------------------------
// Split-bf16 MFMA GEMM: C[M,128] = A[M,GK] @ W[GK,128] (+bias), fp32-grade
// precision via C ~= Ah*Bh + Ah*Bl + Al*Bh (3 MFMAs, 16x16x32 bf16).
// 128x128 block tile; 4 waves in 2x2, each wave a 4x4 grid of 16x16 tiles.
// A is fp32 in global, converted to hi/lo bf16 during LDS staging.
// In-place safe (C==A): a block reads only the 128 rows it later writes,
// and all K-tiles are consumed before the epilogue stores.
// ---------------------------------------------------------------------------
template<int ADD_BIAS>
__global__ __launch_bounds__(256) void gemm_mfma(const float* __restrict__ A,
        int GK, int Kt, int woff, const float* __restrict__ bias, float* __restrict__ C) {
    __shared__ __align__(16) ushort AsH[128][32];
    __shared__ __align__(16) ushort AsL[128][32];
    __shared__ __align__(16) ushort BsH[128][32];
    __shared__ __align__(16) ushort BsL[128][32];
    const int t = threadIdx.x;
    const size_t row0 = (size_t)blockIdx.x * 128;
    const int lane = t & 63, wave = t >> 6;
    const int quad = lane >> 4, l15 = lane & 15;
    const int wm = wave & 1, wn = wave >> 1;
    const int KP = Kt * 32;

    f32x4 acc[4][4];
#pragma unroll
    for (int i = 0; i < 4; i++)
#pragma unroll
        for (int j = 0; j < 4; j++) acc[i][j] = (f32x4){0.f, 0.f, 0.f, 0.f};

    for (int kt = 0; kt < Kt; kt++) {
        const int k0 = kt * 32;
        // ---- stage A (fp32 -> hi/lo bf16) and B (pre-split) tiles ----
#pragma unroll
        for (int ii = 0; ii < 8; ii++) {
            const int i = t + ii * 256;          // 0..2047
            const int r = i >> 4;                // row / n : 0..127
            const int kp = (i & 15) * 2;         // k within tile, pair
            const int kk = k0 + kp;
            const size_t abase = (row0 + r) * (size_t)GK;
            const float a0 = (kk     < GK) ? A[abase + kk]     : 0.f;
            const float a1 = (kk + 1 < GK) ? A[abase + kk + 1] : 0.f;
            const ushort h0 = bf16_rne(a0), h1 = bf16_rne(a1);
            const ushort l0 = bf16_trunc(a0 - bf16_f(h0));
            const ushort l1 = bf16_trunc(a1 - bf16_f(h1));
            *(ushort2*)&AsH[r][kp] = make_ushort2(h0, h1);
            *(ushort2*)&AsL[r][kp] = make_ushort2(l0, l1);
            const int wbase = woff + r * KP + kk;
            *(ushort2*)&BsH[r][kp] = *(const ushort2*)&g_WtH[wbase];
            *(ushort2*)&BsL[r][kp] = *(const ushort2*)&g_WtL[wbase];
        }
        __syncthreads();
        // ---- fragments + MFMA ----
        bf16x8 aH[4], aL[4];
#pragma unroll
        for (int i = 0; i < 4; i++) {
            const int m = wm * 64 + i * 16 + l15;
            aH[i] = *(const bf16x8*)&AsH[m][quad * 8];
            aL[i] = *(const bf16x8*)&AsL[m][quad * 8];
        }
#pragma unroll
        for (int j = 0; j < 4; j++) {
            const int n = wn * 64 + j * 16 + l15;
            const bf16x8 bH = *(const bf16x8*)&BsH[n][quad * 8];
            const bf16x8 bL = *(const bf16x8*)&BsL[n][quad * 8];
#pragma unroll
            for (int i = 0; i < 4; i++) {
                acc[i][j] = __builtin_amdgcn_mfma_f32_16x16x32_bf16(aH[i], bH, acc[i][j], 0, 0, 0);
                acc[i][j] = __builtin_amdgcn_mfma_f32_16x16x32_bf16(aH[i], bL, acc[i][j], 0, 0, 0);
                acc[i][j] = __builtin_amdgcn_mfma_f32_16x16x32_bf16(aL[i], bH, acc[i][j], 0, 0, 0);
            }
        }
        __syncthreads();
    }
    // ---- epilogue: C/D layout col=lane&15, row=quad*4+reg ----
#pragma unroll
    for (int j = 0; j < 4; j++) {
        const int col = wn * 64 + j * 16 + l15;
        const float bv = ADD_BIAS ? bias[col] : 0.f;
#pragma unroll
        for (int i = 0; i < 4; i++) {
            const size_t rbase = row0 + wm * 64 + i * 16 + quad * 4;
#pragma unroll
            for (int rg = 0; rg < 4; rg++) {
                C[(rbase + rg) * CN + col] = acc[i][j][rg] + bv;
            }
        }
    }
}

// ---------------------------------------------------------------------------
// Aggregation (gather CSR), optionally fused conv-bias + eval-BN + ReLU.
// One block per batch entry.
// ---------------------------------------------------------------------------
template<int BN_RELU>
__global__ __launch_bounds__(256) void agg_kernel(const float* __restrict__ tin,
        const int* __restrict__ rowptr, const int* __restrict__ srcs,
        const float* __restrict__ vals,
        const float* __restrict__ conv_b, const float* __restrict__ bn_w,
        const float* __restrict__ bn_b, float* __restrict__ out) {
    const int b = blockIdx.x;
    const int t = threadIdx.x;
    const int c0 = (t & 31) * 4;
    const int ng = t >> 5;

    float4 sc = make_float4(1.f, 1.f, 1.f, 1.f);
    float4 sh = make_float4(0.f, 0.f, 0.f, 0.f);
    if (BN_RELU) {
        const float inv = rsqrtf(1.f + 1e-5f);
        const float4 w  = *(const float4*)(bn_w + c0);
        const float4 bb = *(const float4*)(bn_b + c0);
        const float4 cb = *(const float4*)(conv_b + c0);
        sc = make_float4(w.x * inv, w.y * inv, w.z * inv, w.w * inv);
        sh = make_float4(fmaf(cb.x, sc.x, bb.x), fmaf(cb.y, sc.y, bb.y),
                         fmaf(cb.z, sc.z, bb.z), fmaf(cb.w, sc.w, bb.w));
    }

    const float* tb = tin + (size_t)b * (NN * CN);
    float*       ob = out + (size_t)b * (NN * CN);

    for (int n0 = 0; n0 < NN; n0 += 8) {
        const int n = n0 + ng;
        if (n < NN) {
            const int beg = rowptr[n], end = rowptr[n + 1];
            float4 acc = make_float4(0.f, 0.f, 0.f, 0.f);
            for (int i = beg; i < end; i++) {
                const int s = srcs[i];
                const float v = vals[i];
                const float4 tv = *(const float4*)(tb + s * CN + c0);
                acc.x = fmaf(tv.x, v, acc.x);
                acc.y = fmaf(tv.y, v, acc.y);
                acc.z = fmaf(tv.z, v, acc.z);
                acc.w = fmaf(tv.w, v, acc.w);
            }
            if (BN_RELU) {
                acc.x = fmaxf(fmaf(acc.x, sc.x, sh.x), 0.f);
                acc.y = fmaxf(fmaf(acc.y, sc.y, sh.y), 0.f);
                acc.z = fmaxf(fmaf(acc.z, sc.z, sh.z), 0.f);
                acc.w = fmaxf(fmaf(acc.w, sc.w, sh.w), 0.f);
            }
            *(float4*)(ob + n * CN + c0) = acc;
        }
    }
}

// ---------------------------------------------------------------------------
// Orchestration.
//   d_out : GEMM scratch layers 0/1, aggregated input for layer 2, final out.
//   d_ws  : [CSR header 64KB][bufA 81.8MB]
// Layer 2 uses S*(h@W2)+b2 == (S*h)@W2+b2.
// ---------------------------------------------------------------------------
extern "C" void kernel_launch(void* const* d_in, const int* in_sizes, int n_in,
                              void* d_out, int out_size, void* d_ws, size_t ws_size,
                              hipStream_t stream) {
    const float* x    = (const float*)d_in[0];
    const int*   ei   = (const int*)  d_in[1];
    const float* W0   = (const float*)d_in[2];
    const float* b0   = (const float*)d_in[3];
    const float* bnw0 = (const float*)d_in[4];
    const float* bnb0 = (const float*)d_in[5];
    const float* W1   = (const float*)d_in[6];
    const float* b1   = (const float*)d_in[7];
    const float* bnw1 = (const float*)d_in[8];
    const float* bnb1 = (const float*)d_in[9];
    const float* W2   = (const float*)d_in[10];
    const float* b2   = (const float*)d_in[11];
    float* out = (float*)d_out;

    const int E = in_sizes[1] / 2;

    int*   rowptr = (int*)d_ws;
    int*   srcs   = rowptr + 512;
    float* vals   = (float*)(srcs + 2048);
    float* bufA   = (float*)d_ws + 16384;     // 64 KB offset

    const int gemm_grid = M_ROWS / 128;       // 1248, exact

    prep_kernel<<<1, 256, 0, stream>>>(ei, E, rowptr, srcs, vals);
    wt_kernel<<<(128 * KP0) / 256, 256, 0, stream>>>(W0, 301, KP0, W0_OFF);
    wt_kernel<<<(128 * 128) / 256, 256, 0, stream>>>(W1, 128, 128, W1_OFF);
    wt_kernel<<<(128 * 128) / 256, 256, 0, stream>>>(W2, 128, 128, W2_OFF);

    // Layer 0: t0 = x@W0 -> d_out ; h1 = relu(bn(agg(t0)+b0)) -> bufA
    gemm_mfma<0><<<gemm_grid, 256, 0, stream>>>(x, 301, KP0 / 32, W0_OFF, nullptr, out);
    agg_kernel<1><<<BATCH, 256, 0, stream>>>(out, rowptr, srcs, vals, b0, bnw0, bnb0, bufA);

    // Layer 1: t1 = h1@W1 -> d_out ; h2 = relu(bn(agg(t1)+b1)) -> bufA
    gemm_mfma<0><<<gemm_grid, 256, 0, stream>>>(bufA, 128, 4, W1_OFF, nullptr, out);
    agg_kernel<1><<<BATCH, 256, 0, stream>>>(out, rowptr, srcs, vals, b1, bnw1, bnb1, bufA);

    // Layer 2 (reordered): g = agg(h2) -> d_out ; out = g@W2 + b2 (in-place)
    agg_kernel<0><<<BATCH, 256, 0, stream>>>(bufA, rowptr, srcs, vals, nullptr, nullptr, nullptr, out);
    gemm_mfma<1><<<gemm_grid, 256, 0, stream>>>(out, 128, 4, W2_OFF, b2, out);
}

// Round 3
// 714.602 us; speedup vs baseline: 1.9779x; 1.4528x over previous
//
#include <hip/hip_runtime.h>

// Problem constants (GraphNet_41944650613153)
#define NN    156            // nodes per graph
#define CN    128            // channels
#define BATCH 1024

typedef __attribute__((ext_vector_type(8))) short bf16x8;  // 8 bf16 (4 VGPRs)
typedef __attribute__((ext_vector_type(4))) float f32x4;   // 4 fp32

// Pre-transposed hi/lo-split weights: Wt[n][k] = W[k][n], zero-padded to Kpad.
#define KP0 320
#define W0_OFF 0
#define W1_OFF (128 * KP0)
#define W2_OFF (128 * KP0 + 128 * 128)
__device__ ushort g_WtH[128 * (KP0 + 128 + 128)];
__device__ ushort g_WtL[128 * (KP0 + 128 + 128)];

__device__ __forceinline__ ushort bf16_rne(float f) {
    union { float f; uint32_t u; } v; v.f = f;
    return (ushort)((v.u + 0x7FFFu + ((v.u >> 16) & 1u)) >> 16);
}
__device__ __forceinline__ float bf16_f(ushort h) {
    union { float f; uint32_t u; } v; v.u = ((uint32_t)h) << 16; return v.f;
}
__device__ __forceinline__ ushort bf16_trunc(float f) {
    union { float f; uint32_t u; } v; v.f = f;
    return (ushort)(v.u >> 16);
}

// global -> LDS DMA, 16 B per lane; lds dest = wave-uniform base + lane*16
using gp_t = const __attribute__((address_space(1))) uint8_t*;
using lp_t = __attribute__((address_space(3))) uint8_t*;
__device__ __forceinline__ void dma16(const void* g, void* l) {
    __builtin_amdgcn_global_load_lds((gp_t)g, (lp_t)l, 16, 0, 0);
}

// ---------------------------------------------------------------------------
// prep: degree -> dinv -> CSR (by destination), self-loops included.
// ---------------------------------------------------------------------------
__global__ __launch_bounds__(256) void prep_kernel(const int* __restrict__ ei, int E,
        int* __restrict__ rowptr, int* __restrict__ srcs, float* __restrict__ vals) {
    __shared__ int   cnt[NN];
    __shared__ int   pos[NN];
    __shared__ float dinv_s[NN];
    const int t = threadIdx.x;
    for (int n = t; n < NN; n += 256) cnt[n] = 1;          // self loop
    __syncthreads();
    for (int e = t; e < E; e += 256) atomicAdd(&cnt[ei[E + e]], 1);
    __syncthreads();
    for (int n = t; n < NN; n += 256) dinv_s[n] = rsqrtf((float)cnt[n]);
    __syncthreads();
    if (t == 0) {
        int run = 0;
        for (int n = 0; n < NN; n++) { rowptr[n] = run; pos[n] = run; run += cnt[n]; }
        rowptr[NN] = run;
    }
    __syncthreads();
    for (int e = t; e < E; e += 256) {
        const int r = ei[e], c = ei[E + e];
        const int idx = atomicAdd(&pos[c], 1);
        srcs[idx] = r;
        vals[idx] = dinv_s[r] * dinv_s[c];
    }
    for (int n = t; n < NN; n += 256) {
        const int idx = atomicAdd(&pos[n], 1);
        srcs[idx] = n;
        vals[idx] = dinv_s[n] * dinv_s[n];
    }
}

// ---------------------------------------------------------------------------
// W transpose + hi/lo split into device globals.
// ---------------------------------------------------------------------------
__global__ __launch_bounds__(256) void wt_kernel(const float* __restrict__ W,
        int K, int Kpad, int woff) {
    const int id = blockIdx.x * 256 + threadIdx.x;   // over 128*Kpad, exact
    const int n = id & 127, k = id >> 7;
    const float f = (k < K) ? W[(size_t)k * CN + n] : 0.f;
    const ushort h = bf16_rne(f);
    g_WtH[woff + n * Kpad + k] = h;
    g_WtL[woff + n * Kpad + k] = bf16_trunc(f - bf16_f(h));
}

// ---------------------------------------------------------------------------
// Fused layer: one graph per block.
//   t = A_b @ W           (split-bf16 MFMA, 160x128 tile, result -> LDS)
//   out = agg_CSR(t)      (per-wave private 32-col slice, no barrier)
//   FINAL=0: h' = relu(bn(out + conv_b)) -> split-bf16 planes OH/OL
//   FINAL=1: out + conv_b -> fp32 Ofp
// A_MODE=0: A = fp32 global (x), converted during staging (VGPR path).
// A_MODE=1: A = split planes AH/AL, staged via global_load_lds (zero VALU).
// LDS: staging buffers (36 KB) alias the 80 KB t matrix (t written only
// after the K-loop's final barrier).
// In-place safe for AH/AL == OH/OL: block b reads only graph b (K-loop),
// writes only graph b (epilogue, strictly after).
// ---------------------------------------------------------------------------
template<int A_MODE, int FINAL, int KT_N>
__global__ __launch_bounds__(256, 2) void fused_layer(
        const float* __restrict__ Afp,
        const ushort* __restrict__ AH, const ushort* __restrict__ AL,
        int GK, int woff,
        const int* __restrict__ rowptr, const int* __restrict__ srcs,
        const float* __restrict__ vals,
        const float* __restrict__ conv_b, const float* __restrict__ bn_w,
        const float* __restrict__ bn_b,
        ushort* __restrict__ OH, ushort* __restrict__ OL,
        float* __restrict__ Ofp) {
    __shared__ __align__(16) uint8_t smem[81920];
    ushort* AsH = (ushort*)smem;                  // [160][32]
    ushort* AsL = (ushort*)(smem + 10240);        // [160][32]
    ushort* BsH = (ushort*)(smem + 20480);        // [128][32]
    ushort* BsL = (ushort*)(smem + 28672);        // [128][32]
    float*  tmat = (float*)smem;                  // [160][128] (aliases staging)

    const int t = threadIdx.x;
    const int b = blockIdx.x;
    const int lane = t & 63, wave = t >> 6;
    const int quad = lane >> 4, l15 = lane & 15;
    const size_t arow0 = (size_t)b * NN;
    const int KP = KT_N * 32;                     // padded K of g_Wt planes

    f32x4 acc[10][2];
#pragma unroll
    for (int i = 0; i < 10; i++)
#pragma unroll
        for (int j = 0; j < 2; j++) acc[i][j] = (f32x4){0.f, 0.f, 0.f, 0.f};

    for (int kt = 0; kt < KT_N; kt++) {
        const int k0 = kt * 32;
        // ---- stage B (and A if split planes) via global_load_lds ----
        if (A_MODE == 1) {
            // 36 DMA instrs: 0-9 AsH, 10-19 AsL, 20-27 BsH, 28-35 BsL
            for (int idx = wave; idx < 36; idx += 4) {
                const void* g; void* l;
                if (idx < 20) {
                    const int i = (idx < 10) ? idx : idx - 10;
                    int r = i * 16 + (lane >> 2);
                    r = (r < NN) ? r : (NN - 1);          // clamp pad rows
                    const int kk = k0 + (lane & 3) * 8;
                    const ushort* src = (idx < 10) ? AH : AL;
                    g = src + (arow0 + r) * CN + kk;
                    l = ((idx < 10) ? (uint8_t*)AsH : (uint8_t*)AsL) + i * 1024;
                } else {
                    const int i = (idx < 28) ? idx - 20 : idx - 28;
                    const int n = i * 16 + (lane >> 2);
                    const int kk = k0 + (lane & 3) * 8;
                    const ushort* src = (idx < 28) ? g_WtH : g_WtL;
                    g = src + woff + n * KP + kk;
                    l = ((idx < 28) ? (uint8_t*)BsH : (uint8_t*)BsL) + i * 1024;
                }
                dma16(g, l);
            }
        } else {
            // B planes: 16 DMA instrs
            for (int idx = wave; idx < 16; idx += 4) {
                const int i = (idx < 8) ? idx : idx - 8;
                const int n = i * 16 + (lane >> 2);
                const int kk = k0 + (lane & 3) * 8;
                const ushort* src = (idx < 8) ? g_WtH : g_WtL;
                dma16(src + woff + n * KP + kk,
                      ((idx < 8) ? (uint8_t*)BsH : (uint8_t*)BsL) + i * 1024);
            }
            // A: fp32 load + convert + LDS write (10 dword-pairs per thread)
#pragma unroll
            for (int s = 0; s < 10; s++) {
                const int p = t + s * 256;            // 0..2559
                const int r = p >> 4;                 // 0..159
                const int kp = (p & 15) * 2;          // 0..30
                const int rc = (r < NN) ? r : (NN - 1);
                const size_t abase = (arow0 + rc) * (size_t)GK;
                const int kk = k0 + kp;
                const float a0 = (kk     < GK) ? Afp[abase + kk]     : 0.f;
                const float a1 = (kk + 1 < GK) ? Afp[abase + kk + 1] : 0.f;
                const ushort h0 = bf16_rne(a0), h1 = bf16_rne(a1);
                const ushort l0 = bf16_trunc(a0 - bf16_f(h0));
                const ushort l1 = bf16_trunc(a1 - bf16_f(h1));
                *(ushort2*)&AsH[r * 32 + kp] = make_ushort2(h0, h1);
                *(ushort2*)&AsL[r * 32 + kp] = make_ushort2(l0, l1);
            }
        }
        __syncthreads();
        // ---- MFMA: wave owns cols [32*wave, 32*wave+32), all 160 rows ----
        bf16x8 bH[2], bL[2];
#pragma unroll
        for (int j = 0; j < 2; j++) {
            const int n = wave * 32 + j * 16 + l15;
            bH[j] = *(const bf16x8*)&BsH[n * 32 + quad * 8];
            bL[j] = *(const bf16x8*)&BsL[n * 32 + quad * 8];
        }
#pragma unroll
        for (int i = 0; i < 10; i++) {
            const int m = i * 16 + l15;
            const bf16x8 aH = *(const bf16x8*)&AsH[m * 32 + quad * 8];
            const bf16x8 aL = *(const bf16x8*)&AsL[m * 32 + quad * 8];
#pragma unroll
            for (int j = 0; j < 2; j++) {
                acc[i][j] = __builtin_amdgcn_mfma_f32_16x16x32_bf16(aH, bH[j], acc[i][j], 0, 0, 0);
                acc[i][j] = __builtin_amdgcn_mfma_f32_16x16x32_bf16(aH, bL[j], acc[i][j], 0, 0, 0);
                acc[i][j] = __builtin_amdgcn_mfma_f32_16x16x32_bf16(aL, bH[j], acc[i][j], 0, 0, 0);
            }
        }
        __syncthreads();   // all waves done with As/Bs before next stage / t-write
    }

    // ---- write t (C/D layout: col = l15, row = quad*4 + reg) ----
#pragma unroll
    for (int i = 0; i < 10; i++)
#pragma unroll
        for (int j = 0; j < 2; j++) {
            const int col = wave * 32 + j * 16 + l15;
            const int rowb = i * 16 + quad * 4;
#pragma unroll
            for (int rg = 0; rg < 4; rg++)
                tmat[(rowb + rg) * CN + col] = acc[i][j][rg];
        }
    // no barrier: each wave reads only its own 32-col slice of t

    // ---- aggregation + epilogue (4 cols/lane, 8 nodes per iteration) ----
    const int col0 = wave * 32 + (lane & 7) * 4;
    const int ng = lane >> 3;
    float cb[4], sc[4], sb[4];
#pragma unroll
    for (int c = 0; c < 4; c++) cb[c] = conv_b[col0 + c];
    if (FINAL == 0) {
        const float inv = rsqrtf(1.f + 1e-5f);
#pragma unroll
        for (int c = 0; c < 4; c++) {
            sc[c] = bn_w[col0 + c] * inv;
            sb[c] = bn_b[col0 + c];
        }
    }
    for (int n0 = 0; n0 < NN; n0 += 8) {
        const int n = n0 + ng;
        if (n < NN) {
            const int beg = rowptr[n], end = rowptr[n + 1];
            float a0 = 0.f, a1 = 0.f, a2 = 0.f, a3 = 0.f;
            for (int e = beg; e < end; e++) {
                const int s = srcs[e];
                const float v = vals[e];
                const f32x4 tv = *(const f32x4*)&tmat[s * CN + col0];
                a0 = fmaf(tv[0], v, a0);
                a1 = fmaf(tv[1], v, a1);
                a2 = fmaf(tv[2], v, a2);
                a3 = fmaf(tv[3], v, a3);
            }
            const size_t obase = (arow0 + n) * CN + col0;
            if (FINAL == 0) {
                float r[4] = {a0 + cb[0], a1 + cb[1], a2 + cb[2], a3 + cb[3]};
                ushort4 hs, ls;
                ushort* hp = &hs.x; ushort* lp = &ls.x;
#pragma unroll
                for (int c = 0; c < 4; c++) {
                    const float vv = fmaxf(fmaf(r[c], sc[c], sb[c]), 0.f);
                    const ushort hh = bf16_rne(vv);
                    hp[c] = hh;
                    lp[c] = bf16_trunc(vv - bf16_f(hh));
                }
                *(ushort4*)&OH[obase] = hs;
                *(ushort4*)&OL[obase] = ls;
            } else {
                float4 o = make_float4(a0 + cb[0], a1 + cb[1], a2 + cb[2], a3 + cb[3]);
                *(float4*)&Ofp[obase] = o;
            }
        }
    }
}

// ---------------------------------------------------------------------------
// Orchestration.
// d_ws: [CSR 64 KB][hH plane 40.9 MB][hL plane 40.9 MB]  (round-1 footprint)
// Planes are reused in-place by layers 1 and 2 (per-block read-before-write).
// ---------------------------------------------------------------------------
extern "C" void kernel_launch(void* const* d_in, const int* in_sizes, int n_in,
                              void* d_out, int out_size, void* d_ws, size_t ws_size,
                              hipStream_t stream) {
    const float* x    = (const float*)d_in[0];
    const int*   ei   = (const int*)  d_in[1];
    const float* W0   = (const float*)d_in[2];
    const float* b0   = (const float*)d_in[3];
    const float* bnw0 = (const float*)d_in[4];
    const float* bnb0 = (const float*)d_in[5];
    const float* W1   = (const float*)d_in[6];
    const float* b1   = (const float*)d_in[7];
    const float* bnw1 = (const float*)d_in[8];
    const float* bnb1 = (const float*)d_in[9];
    const float* W2   = (const float*)d_in[10];
    const float* b2   = (const float*)d_in[11];
    float* out = (float*)d_out;

    const int E = in_sizes[1] / 2;

    int*    rowptr = (int*)d_ws;
    int*    srcs   = rowptr + 512;
    float*  vals   = (float*)(srcs + 2048);
    ushort* hH     = (ushort*)((float*)d_ws + 16384);       // 64 KB offset
    ushort* hL     = hH + (size_t)BATCH * NN * CN;          // +40.9 MB

    prep_kernel<<<1, 256, 0, stream>>>(ei, E, rowptr, srcs, vals);
    wt_kernel<<<(128 * KP0) / 256, 256, 0, stream>>>(W0, 301, KP0, W0_OFF);
    wt_kernel<<<(128 * 128) / 256, 256, 0, stream>>>(W1, 128, 128, W1_OFF);
    wt_kernel<<<(128 * 128) / 256, 256, 0, stream>>>(W2, 128, 128, W2_OFF);

    // Layer 0: h1 = relu(bn(agg(x@W0)+b0)) -> planes
    fused_layer<0, 0, 10><<<BATCH, 256, 0, stream>>>(
        x, nullptr, nullptr, 301, W0_OFF, rowptr, srcs, vals,
        b0, bnw0, bnb0, hH, hL, nullptr);
    // Layer 1: h2 = relu(bn(agg(h1@W1)+b1)) -> planes (in-place)
    fused_layer<1, 0, 4><<<BATCH, 256, 0, stream>>>(
        nullptr, hH, hL, CN, W1_OFF, rowptr, srcs, vals,
        b1, bnw1, bnb1, hH, hL, nullptr);
    // Layer 2: out = agg(h2@W2) + b2 -> fp32
    fused_layer<1, 1, 4><<<BATCH, 256, 0, stream>>>(
        nullptr, hH, hL, CN, W2_OFF, rowptr, srcs, vals,
        b2, nullptr, nullptr, nullptr, nullptr, out);
}